// Round 9
// baseline (171.700 us; speedup 1.0000x reference)
//
#include <hip/hip_runtime.h>
#include <hip/hip_bf16.h>

typedef __attribute__((ext_vector_type(8))) short short8;
typedef __attribute__((ext_vector_type(4))) float floatx4;

#define TINV 14.2857142857142857f               // 1/0.07
#define TL2  20.60992915555662f                  // TINV * log2(e)
#define LN2  0.6931471805599453f
#define SQS  4.539816022451927f                  // sqrt(TL2): dot(fb,fb) = TL2*dot(f,f)
#define NROWS 8192
#define NDIM 128
#define NCH 16
#define NITS 16                                  // 16 x 32 cols = 512-col chunk
#define NBLOCKS 2048

__device__ __forceinline__ float fexp2(float x) {
#if __has_builtin(__builtin_amdgcn_exp2f)
    return __builtin_amdgcn_exp2f(x);
#else
    return __expf(x * LN2);
#endif
}

// fp32 -> bf16 (pre-scaled by sqrt(TL2)), written TRANSPOSED into fbT (coalesced).
// Also zeroes out[0] and the 18-word counter/accumulator block in workspace.
__global__ void convert_kernel(const float* __restrict__ in, unsigned short* __restrict__ fbT,
                               float* __restrict__ outz, unsigned int* __restrict__ zws) {
    const int i = blockIdx.x * 256 + threadIdx.x;   // 512 blocks -> 131072 = 16 kc x 8192 rows
    const int kc = i >> 13;
    const int row = i & 8191;
    const float4* p = (const float4*)(in + (size_t)row * NDIM + kc * 8);
    const float4 a = p[0], b = p[1];
    union { short8 s; __hip_bfloat162 h[4]; } t;
    t.h[0] = __float22bfloat162_rn(float2{a.x * SQS, a.y * SQS});
    t.h[1] = __float22bfloat162_rn(float2{a.z * SQS, a.w * SQS});
    t.h[2] = __float22bfloat162_rn(float2{b.x * SQS, b.y * SQS});
    t.h[3] = __float22bfloat162_rn(float2{b.z * SQS, b.w * SQS});
    ((short8*)fbT)[(size_t)kc * NROWS + row] = t.s;
    if (i < 18) zws[i] = 0u;                      // ctrs[16], gctr, nacc
    if (i == 0) outz[0] = 0.0f;
}

// grid 2048, 256-thread blocks: rb = blockIdx&127 (64 rows), q = blockIdx>>7 (512-col chunk).
// BLOCKS-IN-FLIGHT experiment: 1-rowset/wave body (measured VGPR 32) at
// __launch_bounds__(256,8) -> 8 independent blocks/CU (vs the 2.2-2.4 invariant of
// all prior clean rounds). Inner loop byte-identical to the proven round-4 body
// (42.8us). Per-slot stall (~3200cyc vs ~800cyc issue content) should now be
// hidden by 4x block-level parallelism. Fused final via validated rowgroup
// counters (rounds 7+8). Final-phase LDS aliased onto dead stage buffer.
__global__ __launch_bounds__(256, 8) void supcon_main(
    const unsigned short* __restrict__ fbT,
    const int* __restrict__ labels,
    float* __restrict__ sM, float* __restrict__ sS, float* __restrict__ sP,
    unsigned int* __restrict__ ctrs,      // [16] rowgroup counters, [16]=gctr, [17]=nacc
    float* __restrict__ out)
{
    __shared__ __align__(16) short stage[2][16 * 32 * 8];   // [buf][kc][col] 16B units, 8KB each
    __shared__ float nredW[4];
    __shared__ int amLast, amNoise;

    // final-phase arrays aliased onto stage[0] (dead after the main loop + barrier)
    int*   lab3  = (int*)&stage[0][0];            // 512 ints = 2048B
    int*   hist3 = (int*)&stage[0][1024];         // 16 ints
    float* red3  = (float*)&stage[0][1056];       // 256 floats

    unsigned int* gctr = ctrs + 16;
    float* nacc = (float*)(ctrs + 17);

    const int rb = blockIdx.x & 127;
    const int q  = blockIdx.x >> 7;
    const int rg = rb >> 3;                       // rowgroup 0..15 (512 rows each)
    const int rowBase = rb << 6;
    const int colBase = q << 9;
    const int tid = threadIdx.x;
    const int w = __builtin_amdgcn_readfirstlane(tid >> 6);   // wave id 0..3 -> SGPR
    const int lane = tid & 63;
    const int l15 = lane & 15;
    const int l4  = lane >> 4;
    const int kc_hi = lane >> 5;        // 0/1: which kc within the pair this lane loads
    const int col_l = lane & 31;

    const short8* fb8 = (const short8*)fbT;

// issue staging for tile IT into buffer BUF: 2 instrs/wave, each 1KB = 2 kc-rows x 32 cols
#define ISSUE(IT, BUF)                                                                   \
    {                                                                                    \
        unsigned short* sbase = (unsigned short*)&stage[BUF][0];                         \
        _Pragma("unroll")                                                                \
        for (int j = 0; j < 2; ++j) {                                                    \
            const int kcb = (w << 2) + (j << 1);                                         \
            const unsigned short* src = fbT +                                            \
                ((size_t)(kcb + kc_hi) * NROWS + colBase + ((IT) << 5) + col_l) * 8;     \
            __builtin_amdgcn_global_load_lds(                                            \
                (const __attribute__((address_space(1))) unsigned int*)src,              \
                (__attribute__((address_space(3))) unsigned int*)(sbase + kcb * 256),    \
                16, 0, 0);                                                               \
        }                                                                                \
    }

    ISSUE(0, 0)

    // A fragments: wave owns 16 rows (one rowset); from fbT (coalesced 256B segs)
    const int rw = rowBase + w * 16;                 // SGPR
    const int brow = rw >> 4;
    const int lrow = labels[brow];                    // uniform addr -> s_load
    short8 afrag[4];
    #pragma unroll
    for (int t = 0; t < 4; ++t)
        afrag[t] = fb8[(size_t)(t * 4 + l4) * NROWS + rw + l15];

    // scalar class-match mask over the 32 col-16 tiles of this chunk
    const int cb16 = colBase >> 4;
    unsigned pms = 0u;
    #pragma unroll
    for (int c = 0; c < 32; ++c)
        if (labels[cb16 + c] == lrow) pms |= (1u << c);

    float tm[4], su[4], ps[4];
    #pragma unroll
    for (int r = 0; r < 4; ++r) { tm[r] = -1e30f; su[r] = 0.0f; ps[r] = 0.0f; }
    float noise_acc = 0.0f;

    for (int it = 0; it < NITS; ++it) {
        __syncthreads();                 // drains my tile-it loads (vmcnt 0) + barrier
        if (it + 1 < NITS) ISSUE(it + 1, (it + 1) & 1)

        const short8* stv = (const short8*)stage[it & 1];
        floatx4 vacc[2];
        #pragma unroll
        for (int c = 0; c < 2; ++c) {
            floatx4 acc = {0.0f, 0.0f, 0.0f, 0.0f};
            #pragma unroll
            for (int t = 0; t < 4; ++t) {
                short8 bfrag = stv[(t * 4 + l4) * 32 + (c << 4) + l15];  // 2-way bank = free
                acc = __builtin_amdgcn_mfma_f32_16x16x32_bf16(afrag[t], bfrag, acc, 0, 0, 0);
            }
            vacc[c] = acc;
        }

        const int base16 = cb16 + (it << 1);
        const int nt = brow - base16;          // same-batch tile index if in [0,2) — scalar
        const bool anyn = ((unsigned)nt) < 2u; // wave-uniform scalar
        int posm = (int)((pms >> (it << 1)) & 3u);
        if (anyn) posm &= ~(1 << nt);          // drop same-batch tile from positives
        #pragma unroll
        for (int r = 0; r < 4; ++r) {
            const float v0 = vacc[0][r], v1 = vacc[1][r];
            if (!anyn) {
                const float lmax = fmaxf(v0, v1);
                const float tmr = tm[r];
                if (__any(lmax > tmr)) {
                    const float tnm = fmaxf(tmr, lmax);
                    su[r] = fmaf(su[r], fexp2(tmr - tnm),
                                 fexp2(v0 - tnm) + fexp2(v1 - tnm));
                    tm[r] = tnm;
                } else {   // steady state: no rescale
                    su[r] += fexp2(v0 - tmr) + fexp2(v1 - tmr);
                }
            } else {       // one of the two 16-tiles is same-batch (invalid + noise)
                const float vv = nt ? v0 : v1;   // the valid tile's value
                const float vn = nt ? v1 : v0;   // the same-batch tile's value
                const float tmr = tm[r];
                const float tnm = fmaxf(tmr, vv);
                su[r] = fmaf(su[r], fexp2(tmr - tnm), fexp2(vv - tnm));
                tm[r] = tnm;
                const int rl = (l4 << 2) + r;
                if ((rl >> 3) == (l15 >> 3) && rl != l15) noise_acc += vn;
            }
            if (posm & 1) ps[r] += v0;
            if (posm & 2) ps[r] += v1;
        }
    }
#undef ISSUE

    // combine the 16 lane-partials per row via shuffles (l15 groups hold one row)
    #pragma unroll
    for (int r = 0; r < 4; ++r) {
        float tmv = tm[r], suv = su[r], psv = ps[r];
        #pragma unroll
        for (int off = 1; off < 16; off <<= 1) {
            float om = __shfl_xor(tmv, off);
            float os = __shfl_xor(suv, off);
            float op = __shfl_xor(psv, off);
            float nm = fmaxf(tmv, om);
            suv = suv * fexp2(tmv - nm) + os * fexp2(om - nm);
            tmv = nm; psv += op;
        }
        if (l15 == 0) {
            int row = rw + (l4 << 2) + r;
            sM[row * NCH + q] = tmv;
            sS[row * NCH + q] = suv;
            sP[row * NCH + q] = psv;
        }
    }

    float na = noise_acc;
    #pragma unroll
    for (int off = 32; off >= 1; off >>= 1) na += __shfl_xor(na, off);
    if (lane == 0) nredW[w] = na;
    __syncthreads();   // drains sM/sS/sP stores (vmcnt 0); stage now dead -> alias OK

    // ---- completion protocol (validated rounds 7+8) ----
    if (tid == 0) {
        float s = nredW[0] + nredW[1] + nredW[2] + nredW[3];
        atomicAdd(nacc, s);                       // device-scope (m20)
        __threadfence();                          // release: wbl2 before counter bumps
        const unsigned o1 = atomicAdd(&ctrs[rg], 1u);
        amLast = (o1 == 127u);                    // all 128 blocks of this rowgroup done
        const unsigned o2 = atomicAdd(gctr, 1u);
        amNoise = (o2 == NBLOCKS - 1u);           // all blocks done -> nacc complete
    }
    __syncthreads();

    if (amLast) {                                 // block-uniform
        __threadfence();                          // acquire: before reading sM/sS/sP
        if (tid < 16) hist3[tid] = 0;
        lab3[tid] = labels[tid];
        lab3[tid + 256] = labels[tid + 256];
        __syncthreads();
        atomicAdd(&hist3[lab3[tid] & 15], 1);
        atomicAdd(&hist3[lab3[tid + 256] & 15], 1);
        __syncthreads();

        float facc = 0.0f;
        #pragma clang loop unroll(disable)        // keep finisher register-light
        for (int rr = 0; rr < 2; ++rr) {
            const int row = (rg << 9) + (rr << 8) + tid;
            const float4* M4 = (const float4*)(sM + (size_t)row * NCH);
            const float4* S4 = (const float4*)(sS + (size_t)row * NCH);
            const float4* P4 = (const float4*)(sP + (size_t)row * NCH);
            float gm = -1e30f;
            #pragma unroll
            for (int j = 0; j < 4; ++j) {
                float4 a = M4[j];
                gm = fmaxf(gm, fmaxf(fmaxf(a.x, a.y), fmaxf(a.z, a.w)));
            }
            float gs = 0.0f, gp = 0.0f;
            #pragma unroll
            for (int j = 0; j < 4; ++j) {
                float4 a = M4[j]; float4 b = S4[j]; float4 c = P4[j];
                gs += b.x * fexp2(a.x - gm) + b.y * fexp2(a.y - gm)
                    + b.z * fexp2(a.z - gm) + b.w * fexp2(a.w - gm);
                gp += c.x + c.y + c.z + c.w;
            }
            const float P = 16.0f * (float)(hist3[lab3[row >> 4] & 15] - 1);
            facc += LN2 * (P * (gm + __log2f(gs)) - gp) / (P + 1e-8f);
        }
        red3[tid] = facc;
        __syncthreads();
        #pragma unroll
        for (int off = 128; off > 0; off >>= 1) {
            if (tid < off) red3[tid] += red3[tid + off];
            __syncthreads();
        }
        if (tid == 0) atomicAdd(out, red3[0] * (1.0f / (8192.0f * 3.0f)));
    }

    if (amNoise && tid == 0) {                    // last block overall: noise term
        __threadfence();
        const float nz = __hip_atomic_load(nacc, __ATOMIC_RELAXED, __HIP_MEMORY_SCOPE_AGENT);
        atomicAdd(out, nz * (-LN2 / (57344.0f * 0.07f * 3.0f)));
    }
}

extern "C" void kernel_launch(void* const* d_in, const int* in_sizes, int n_in,
                              void* d_out, int out_size, void* d_ws, size_t ws_size,
                              hipStream_t stream) {
    const float* feat  = (const float*)d_in[0];
    const int* labels  = (const int*)d_in[1];
    float* out = (float*)d_out;

    unsigned short* fbT = (unsigned short*)d_ws;                   // 2 MB bf16 transposed
    float* wsf  = (float*)((char*)d_ws + (size_t)NROWS * NDIM * 2);
    float* sM   = wsf;                     // 8192*16
    float* sS   = wsf + 131072;
    float* sP   = wsf + 262144;
    unsigned int* ctrs = (unsigned int*)(wsf + 393216);   // [16] rowgroup, [16] gctr, [17] nacc

    hipLaunchKernelGGL(convert_kernel, dim3(512), dim3(256), 0, stream, feat, fbT, out, ctrs);
    hipLaunchKernelGGL(supcon_main, dim3(NBLOCKS), dim3(256), 0, stream,
                       fbT, labels, sM, sS, sP, ctrs, out);
}